// Round 1
// baseline (116.029 us; speedup 1.0000x reference)
//
#include <hip/hip_runtime.h>
#include <hip/hip_bf16.h>

#define NN 50000
#define DEG 16
#define EE (NN*DEG)

typedef unsigned int uint;

__device__ inline uint pk2(float a, float b){
  __hip_bfloat16 ha = __float2bfloat16(a);
  __hip_bfloat16 hb = __float2bfloat16(b);
  unsigned short ua = *reinterpret_cast<unsigned short*>(&ha);
  unsigned short ub = *reinterpret_cast<unsigned short*>(&hb);
  return (uint)ua | ((uint)ub << 16);
}

// K1: out_row = in_row @ W (128x64), bf16 out; s1 = out_row . a[0:64], s2 = out_row . a[64:128] (fp32)
__global__ __launch_bounds__(256) void gemm_s_kernel(
    const float* __restrict__ in, const float* __restrict__ W,
    const float* __restrict__ avec,
    __hip_bfloat16* __restrict__ outb,
    float* __restrict__ s1, float* __restrict__ s2)
{
  __shared__ float Ws[128*64];
  __shared__ float As[128];
  const int tid = threadIdx.x;
  {
    const float4* Wg = (const float4*)W;
    float4* Wl = (float4*)Ws;
    #pragma unroll
    for (int i = 0; i < 8; i++) Wl[i*256 + tid] = Wg[i*256 + tid];
    if (tid < 128) As[tid] = avec[tid];
  }
  __syncthreads();
  const int r = blockIdx.x*64 + (tid >> 2);
  const int q = tid & 3;                  // col quarter: cols q*16 .. q*16+15
  if (r >= NN) return;
  float acc[16];
  #pragma unroll
  for (int j = 0; j < 16; j++) acc[j] = 0.f;
  const float4* inr = (const float4*)(in + (long)r*128);
  const float4* Ws4 = (const float4*)Ws;
  for (int k4 = 0; k4 < 32; k4++) {
    float4 a4 = inr[k4];
    #pragma unroll
    for (int kk = 0; kk < 4; kk++) {
      const float av = kk==0 ? a4.x : kk==1 ? a4.y : kk==2 ? a4.z : a4.w;
      const int k = k4*4 + kk;
      #pragma unroll
      for (int j = 0; j < 4; j++) {
        float4 w = Ws4[k*16 + q*4 + j];
        acc[j*4+0] = fmaf(av, w.x, acc[j*4+0]);
        acc[j*4+1] = fmaf(av, w.y, acc[j*4+1]);
        acc[j*4+2] = fmaf(av, w.z, acc[j*4+2]);
        acc[j*4+3] = fmaf(av, w.w, acc[j*4+3]);
      }
    }
  }
  // fp32 attention scalars (exact path, independent of bf16 storage)
  float p1 = 0.f, p2 = 0.f;
  #pragma unroll
  for (int j = 0; j < 16; j++) {
    p1 = fmaf(acc[j], As[q*16 + j], p1);
    p2 = fmaf(acc[j], As[64 + q*16 + j], p2);
  }
  p1 += __shfl_xor(p1, 1); p1 += __shfl_xor(p1, 2);
  p2 += __shfl_xor(p2, 1); p2 += __shfl_xor(p2, 2);
  if (q == 0) { s1[r] = p1; s2[r] = p2; }
  uint4 v0, v1;
  v0.x = pk2(acc[0],  acc[1]);  v0.y = pk2(acc[2],  acc[3]);
  v0.z = pk2(acc[4],  acc[5]);  v0.w = pk2(acc[6],  acc[7]);
  v1.x = pk2(acc[8],  acc[9]);  v1.y = pk2(acc[10], acc[11]);
  v1.z = pk2(acc[12], acc[13]); v1.w = pk2(acc[14], acc[15]);
  uint4* op = (uint4*)(outb + (long)r*64 + q*16);
  op[0] = v0; op[1] = v1;
}

// K2: wave-per-node attention + gather-accumulate + fp64 partial sums for variance
__global__ __launch_bounds__(256) void attn_kernel(
    const __hip_bfloat16* __restrict__ hvb, const __hip_bfloat16* __restrict__ evb,
    const float* __restrict__ s1n, const float* __restrict__ s2n,
    const float* __restrict__ s1e, const float* __restrict__ s2e,
    const int* __restrict__ edges,
    float* __restrict__ outp, double* __restrict__ partials)
{
  const int tid  = threadIdx.x;
  const int wv   = tid >> 6;
  const int lane = tid & 63;
  double a_sn = 0.0, a_qn = 0.0, a_se = 0.0, a_qe = 0.0;
  float* node_out = outp;
  float* edge_out = outp + (long)NN*128;
  for (int i = blockIdx.x*4 + wv; i < NN; i += gridDim.x*4) {
    const float hv_i = __bfloat162float(hvb[(long)i*64 + lane]);
    const float ev_i = __bfloat162float(evb[(long)i*64 + lane]);
    const float s1ni = s1n[i];
    const float s1ei = s1e[i];
    int dk = 0;
    float attn = 0.f, atte = 0.f;
    if (lane < 16) {
      dk = edges[((long)i*16 + lane)*2 + 1];
      float xn = s1ni + s2n[dk];
      float xe = s1ei + s2e[dk];
      xn = xn > 0.f ? xn : 0.2f*xn;
      xe = xe > 0.f ? xe : 0.2f*xe;
      xn = fminf(fmaxf(xn, -2.f), 2.f);
      xe = fminf(fmaxf(xe, -2.f), 2.f);
      attn = expf(xn);
      atte = expf(xe);
    }
    float sn = attn, se = atte;
    #pragma unroll
    for (int off = 1; off < 64; off <<= 1) {
      sn += __shfl_xor(sn, off);
      se += __shfl_xor(se, off);
    }
    const float wn = attn / sn;   // lanes >=16: 0
    const float we = atte / se;
    float rs_n = wn, rq_n = wn*wn, rs_e = we, rq_e = we*we;
    #pragma unroll
    for (int off = 1; off < 64; off <<= 1) {
      rs_n += __shfl_xor(rs_n, off);
      rq_n += __shfl_xor(rq_n, off);
      rs_e += __shfl_xor(rs_e, off);
      rq_e += __shfl_xor(rq_e, off);
    }
    a_sn += (double)rs_n; a_qn += (double)rq_n;
    a_se += (double)rs_e; a_qe += (double)rq_e;
    float accn = 0.f, acce = 0.f;
    #pragma unroll
    for (int k = 0; k < 16; k++) {
      const int d    = __shfl(dk, k);
      const float wnk = __shfl(wn, k);
      const float wek = __shfl(we, k);
      accn = fmaf(wnk, __bfloat162float(hvb[(long)d*64 + lane]), accn);
      acce = fmaf(wek, __bfloat162float(evb[(long)d*64 + lane]), acce);
    }
    node_out[(long)i*128 + lane]      = hv_i;
    node_out[(long)i*128 + 64 + lane] = accn;
    edge_out[(long)i*128 + lane]      = ev_i;
    edge_out[(long)i*128 + 64 + lane] = acce;
  }
  __shared__ double red[4][4];
  if (lane == 0) { red[wv][0]=a_sn; red[wv][1]=a_qn; red[wv][2]=a_se; red[wv][3]=a_qe; }
  __syncthreads();
  if (tid == 0) {
    double t0=0,t1=0,t2=0,t3=0;
    #pragma unroll
    for (int w=0; w<4; w++){ t0+=red[w][0]; t1+=red[w][1]; t2+=red[w][2]; t3+=red[w][3]; }
    double* p = partials + (long)blockIdx.x*4;
    p[0]=t0; p[1]=t1; p[2]=t2; p[3]=t3;
  }
}

// K3: reduce partials -> the two variance scalars
__global__ __launch_bounds__(256) void finalize_kernel(
    const double* __restrict__ partials, int nparts, float* __restrict__ outp)
{
  const int tid = threadIdx.x;
  double l0=0,l1=0,l2=0,l3=0;
  for (int b = tid; b < nparts; b += 256) {
    l0 += partials[b*4+0]; l1 += partials[b*4+1];
    l2 += partials[b*4+2]; l3 += partials[b*4+3];
  }
  __shared__ double red[256][4];
  red[tid][0]=l0; red[tid][1]=l1; red[tid][2]=l2; red[tid][3]=l3;
  __syncthreads();
  for (int s = 128; s > 0; s >>= 1) {
    if (tid < s) {
      red[tid][0]+=red[tid+s][0]; red[tid][1]+=red[tid+s][1];
      red[tid][2]+=red[tid+s][2]; red[tid][3]+=red[tid+s][3];
    }
    __syncthreads();
  }
  if (tid == 0) {
    const double E = (double)EE;
    double varn = (red[0][1] - red[0][0]*red[0][0]/E) / (E - 1.0);
    double vare = (red[0][3] - red[0][2]*red[0][2]/E) / (E - 1.0);
    outp[(long)NN*256 + 0] = (float)varn;
    outp[(long)NN*256 + 1] = (float)vare;
  }
}

extern "C" void kernel_launch(void* const* d_in, const int* in_sizes, int n_in,
                              void* d_out, int out_size, void* d_ws, size_t ws_size,
                              hipStream_t stream)
{
  const float* node_fts = (const float*)d_in[0];
  const float* edge_fts = (const float*)d_in[1];
  const int*   edges    = (const int*)d_in[2];
  const float* W_node   = (const float*)d_in[3];
  const float* W_edge   = (const float*)d_in[4];
  const float* a_node   = (const float*)d_in[5];
  const float* a_edge   = (const float*)d_in[6];

  char* ws = (char*)d_ws;
  __hip_bfloat16* hvb = (__hip_bfloat16*)(ws);
  __hip_bfloat16* evb = (__hip_bfloat16*)(ws + 6400000);
  float* s1n = (float*)(ws + 12800000);
  float* s2n = (float*)(ws + 13000000);
  float* s1e = (float*)(ws + 13200000);
  float* s2e = (float*)(ws + 13400000);
  double* partials = (double*)(ws + 13600000);
  float* outp = (float*)d_out;

  const int GB = (NN + 63)/64;   // 782 blocks per GEMM
  hipLaunchKernelGGL(gemm_s_kernel, dim3(GB), dim3(256), 0, stream,
                     node_fts, W_node, a_node, hvb, s1n, s2n);
  hipLaunchKernelGGL(gemm_s_kernel, dim3(GB), dim3(256), 0, stream,
                     edge_fts, W_edge, a_edge, evb, s1e, s2e);
  const int AB = 1024;
  hipLaunchKernelGGL(attn_kernel, dim3(AB), dim3(256), 0, stream,
                     hvb, evb, s1n, s2n, s1e, s2e, edges, outp, partials);
  hipLaunchKernelGGL(finalize_kernel, dim3(1), dim3(256), 0, stream,
                     partials, AB, outp);
}

// Round 2
// 96.987 us; speedup vs baseline: 1.1963x; 1.1963x over previous
//
#include <hip/hip_runtime.h>
#include <hip/hip_bf16.h>

#define NN 50000
#define DEG 16
#define EE (NN*DEG)

typedef unsigned int uint;

__device__ inline uint pk2(float a, float b){
  __hip_bfloat16 ha = __float2bfloat16(a);
  __hip_bfloat16 hb = __float2bfloat16(b);
  unsigned short ua = *reinterpret_cast<unsigned short*>(&ha);
  unsigned short ub = *reinterpret_cast<unsigned short*>(&hb);
  return (uint)ua | ((uint)ub << 16);
}

// K1: out_row = in_row @ W (128x64), bf16 out; s1 = out_row . a[0:64], s2 = out_row . a[64:128]
// grid.y selects (node, edge) pass. s1/s2 stored interleaved: s[r*2+pass].
__global__ __launch_bounds__(256) void gemm_s_kernel(
    const float* __restrict__ in0, const float* __restrict__ in1,
    const float* __restrict__ W0,  const float* __restrict__ W1,
    const float* __restrict__ a0,  const float* __restrict__ a1,
    __hip_bfloat16* __restrict__ out0, __hip_bfloat16* __restrict__ out1,
    float* __restrict__ s1ne, float* __restrict__ s2ne)
{
  const int pass = blockIdx.y;
  const float* in   = pass ? in1 : in0;
  const float* W    = pass ? W1  : W0;
  const float* avec = pass ? a1  : a0;
  __hip_bfloat16* outb = pass ? out1 : out0;

  __shared__ float Ws[128*64];
  __shared__ float As[128];
  const int tid = threadIdx.x;
  {
    const float4* Wg = (const float4*)W;
    float4* Wl = (float4*)Ws;
    #pragma unroll
    for (int i = 0; i < 8; i++) Wl[i*256 + tid] = Wg[i*256 + tid];
    if (tid < 128) As[tid] = avec[tid];
  }
  __syncthreads();
  const int r = blockIdx.x*64 + (tid >> 2);
  const int q = tid & 3;                  // col quarter: cols q*16 .. q*16+15
  if (r >= NN) return;
  float acc[16];
  #pragma unroll
  for (int j = 0; j < 16; j++) acc[j] = 0.f;
  const float4* inr = (const float4*)(in + (long)r*128);
  const float4* Ws4 = (const float4*)Ws;
  for (int k4 = 0; k4 < 32; k4++) {
    float4 a4 = inr[k4];
    #pragma unroll
    for (int kk = 0; kk < 4; kk++) {
      const float av = kk==0 ? a4.x : kk==1 ? a4.y : kk==2 ? a4.z : a4.w;
      const int k = k4*4 + kk;
      #pragma unroll
      for (int j = 0; j < 4; j++) {
        float4 w = Ws4[k*16 + q*4 + j];
        acc[j*4+0] = fmaf(av, w.x, acc[j*4+0]);
        acc[j*4+1] = fmaf(av, w.y, acc[j*4+1]);
        acc[j*4+2] = fmaf(av, w.z, acc[j*4+2]);
        acc[j*4+3] = fmaf(av, w.w, acc[j*4+3]);
      }
    }
  }
  float p1 = 0.f, p2 = 0.f;
  #pragma unroll
  for (int j = 0; j < 16; j++) {
    p1 = fmaf(acc[j], As[q*16 + j], p1);
    p2 = fmaf(acc[j], As[64 + q*16 + j], p2);
  }
  p1 += __shfl_xor(p1, 1); p1 += __shfl_xor(p1, 2);
  p2 += __shfl_xor(p2, 1); p2 += __shfl_xor(p2, 2);
  if (q == 0) { s1ne[(long)r*2 + pass] = p1; s2ne[(long)r*2 + pass] = p2; }
  uint4 v0, v1;
  v0.x = pk2(acc[0],  acc[1]);  v0.y = pk2(acc[2],  acc[3]);
  v0.z = pk2(acc[4],  acc[5]);  v0.w = pk2(acc[6],  acc[7]);
  v1.x = pk2(acc[8],  acc[9]);  v1.y = pk2(acc[10], acc[11]);
  v1.z = pk2(acc[12], acc[13]); v1.w = pk2(acc[14], acc[15]);
  uint4* op = (uint4*)(outb + (long)r*64 + q*16);
  op[0] = v0; op[1] = v1;
}

// K2: wave-per-node attention + gather-accumulate + fp64 partial sum-of-squares.
// Sum of normalized weights per node == 1 by construction, so only sum(w^2) is reduced.
__global__ __launch_bounds__(256) void attn_kernel(
    const __hip_bfloat16* __restrict__ hvb, const __hip_bfloat16* __restrict__ evb,
    const float2* __restrict__ s1ne, const float2* __restrict__ s2ne,
    const int* __restrict__ edges,
    float* __restrict__ outp, double* __restrict__ partials)
{
  const int tid  = threadIdx.x;
  const int wv   = tid >> 6;
  const int lane = tid & 63;
  double a_qn = 0.0, a_qe = 0.0;
  float* node_out = outp;
  float* edge_out = outp + (long)NN*128;
  for (int i = blockIdx.x*4 + wv; i < NN; i += gridDim.x*4) {
    const float hv_i = __bfloat162float(hvb[(long)i*64 + lane]);
    const float ev_i = __bfloat162float(evb[(long)i*64 + lane]);
    const float2 s1v = s1ne[i];
    int dk = 0;
    float attn = 0.f, atte = 0.f;
    if (lane < 16) {
      dk = edges[((long)i*16 + lane)*2 + 1];
      const float2 g = s2ne[dk];
      float xn = s1v.x + g.x;
      float xe = s1v.y + g.y;
      xn = xn > 0.f ? xn : 0.2f*xn;
      xe = xe > 0.f ? xe : 0.2f*xe;
      xn = fminf(fmaxf(xn, -2.f), 2.f);
      xe = fminf(fmaxf(xe, -2.f), 2.f);
      attn = expf(xn);
      atte = expf(xe);
    }
    // 16-lane group reduction (scores live only in lanes 0..15)
    float sn = attn, se = atte;
    #pragma unroll
    for (int off = 1; off < 16; off <<= 1) {
      sn += __shfl_xor(sn, off);
      se += __shfl_xor(se, off);
    }
    float wn = 0.f, we = 0.f;
    if (lane < 16) { wn = attn / sn; we = atte / se; }
    float rq_n = wn*wn, rq_e = we*we;
    #pragma unroll
    for (int off = 1; off < 16; off <<= 1) {
      rq_n += __shfl_xor(rq_n, off);
      rq_e += __shfl_xor(rq_e, off);
    }
    if (lane == 0) { a_qn += (double)rq_n; a_qe += (double)rq_e; }
    float accn = 0.f, acce = 0.f;
    #pragma unroll
    for (int k = 0; k < 16; k++) {
      const int d     = __shfl(dk, k);
      const float wnk = __shfl(wn, k);
      const float wek = __shfl(we, k);
      accn = fmaf(wnk, __bfloat162float(hvb[(long)d*64 + lane]), accn);
      acce = fmaf(wek, __bfloat162float(evb[(long)d*64 + lane]), acce);
    }
    node_out[(long)i*128 + lane]      = hv_i;
    node_out[(long)i*128 + 64 + lane] = accn;
    edge_out[(long)i*128 + lane]      = ev_i;
    edge_out[(long)i*128 + 64 + lane] = acce;
  }
  __shared__ double red[4][2];
  if (lane == 0) { red[wv][0] = a_qn; red[wv][1] = a_qe; }
  __syncthreads();
  if (tid == 0) {
    double t0 = 0, t1 = 0;
    #pragma unroll
    for (int w = 0; w < 4; w++) { t0 += red[w][0]; t1 += red[w][1]; }
    double* p = partials + (long)blockIdx.x*2;
    p[0] = t0; p[1] = t1;
  }
}

// K3: reduce partials -> the two variance scalars (sum of weights is exactly N)
__global__ __launch_bounds__(256) void finalize_kernel(
    const double* __restrict__ partials, int nparts, float* __restrict__ outp)
{
  const int tid = threadIdx.x;
  double l0 = 0, l1 = 0;
  for (int b = tid; b < nparts; b += 256) {
    l0 += partials[b*2+0]; l1 += partials[b*2+1];
  }
  __shared__ double red[256][2];
  red[tid][0] = l0; red[tid][1] = l1;
  __syncthreads();
  for (int s = 128; s > 0; s >>= 1) {
    if (tid < s) {
      red[tid][0] += red[tid+s][0];
      red[tid][1] += red[tid+s][1];
    }
    __syncthreads();
  }
  if (tid == 0) {
    const double E = (double)EE;
    const double S = (double)NN;   // sum of normalized weights == 1 per node
    double varn = (red[0][0] - S*S/E) / (E - 1.0);
    double vare = (red[0][1] - S*S/E) / (E - 1.0);
    outp[(long)NN*256 + 0] = (float)varn;
    outp[(long)NN*256 + 1] = (float)vare;
  }
}

extern "C" void kernel_launch(void* const* d_in, const int* in_sizes, int n_in,
                              void* d_out, int out_size, void* d_ws, size_t ws_size,
                              hipStream_t stream)
{
  const float* node_fts = (const float*)d_in[0];
  const float* edge_fts = (const float*)d_in[1];
  const int*   edges    = (const int*)d_in[2];
  const float* W_node   = (const float*)d_in[3];
  const float* W_edge   = (const float*)d_in[4];
  const float* a_node   = (const float*)d_in[5];
  const float* a_edge   = (const float*)d_in[6];

  char* ws = (char*)d_ws;
  __hip_bfloat16* hvb = (__hip_bfloat16*)(ws);
  __hip_bfloat16* evb = (__hip_bfloat16*)(ws + 6400000);
  float* s1ne = (float*)(ws + 12800000);
  float* s2ne = (float*)(ws + 13200000);
  double* partials = (double*)(ws + 13600000);
  float* outp = (float*)d_out;

  const int GB = (NN + 63)/64;   // 782 blocks per pass
  hipLaunchKernelGGL(gemm_s_kernel, dim3(GB, 2), dim3(256), 0, stream,
                     node_fts, edge_fts, W_node, W_edge, a_node, a_edge,
                     hvb, evb, s1ne, s2ne);
  const int AB = 2048;
  hipLaunchKernelGGL(attn_kernel, dim3(AB), dim3(256), 0, stream,
                     hvb, evb, (const float2*)s1ne, (const float2*)s2ne,
                     edges, outp, partials);
  hipLaunchKernelGGL(finalize_kernel, dim3(1), dim3(256), 0, stream,
                     partials, AB, outp);
}

// Round 4
// 77.423 us; speedup vs baseline: 1.4986x; 1.2527x over previous
//
#include <hip/hip_runtime.h>
#include <hip/hip_bf16.h>

#define NN 50000
#define DEG 16
#define EE (NN*DEG)
#define CHUNKS 3125   // NN/16

typedef unsigned int uint;
typedef __attribute__((ext_vector_type(8))) short bf16x8;
typedef __attribute__((ext_vector_type(4))) float f32x4;

// fp32 -> bf16 round-to-nearest-even (finite inputs)
__device__ inline unsigned short f2b(float f){
  uint u = __float_as_uint(f);
  uint r = (u + 0x7FFFu + ((u >> 16) & 1u)) >> 16;
  return (unsigned short)r;
}

// K1: bf16 MFMA GEMM. Per wave: 16 rows x 64 cols over K=128.
// Writes: fp32 first-half of final output (node/edge_out[:, :64] == h_v since sum(w)=1),
//         bf16 gather table, fp32 s1/s2 score scalars.
__global__ __launch_bounds__(256) void gemm_mfma_kernel(
    const float* __restrict__ in0, const float* __restrict__ in1,
    const float* __restrict__ W0,  const float* __restrict__ W1,
    const float* __restrict__ a0,  const float* __restrict__ a1,
    unsigned short* __restrict__ tab0, unsigned short* __restrict__ tab1,
    float* __restrict__ s1ne, float* __restrict__ s2ne,
    float* __restrict__ outp)
{
  const int pass = blockIdx.y;
  const float* in   = pass ? in1 : in0;
  const float* W    = pass ? W1  : W0;
  const float* av   = pass ? a1  : a0;
  unsigned short* tab = pass ? tab1 : tab0;
  float* outhalf = outp + (long)pass * NN * 128;

  // Stage W transposed (Wt[n][k], bf16) into LDS with 16B-block XOR swizzle.
  // 64 n-rows x 16 k-blocks of 8 = 1024 16B chunks (full K=128).
  __shared__ unsigned short Wt[64*128];  // 16 KB
  const int tid = threadIdx.x;
  for (int b = tid; b < 1024; b += 256) {
    const int n  = b >> 4;          // 0..63
    const int k0 = (b & 15) * 8;    // 0..120
    uint4 pk;
    unsigned short* ps = (unsigned short*)&pk;
    #pragma unroll
    for (int j = 0; j < 8; j++) ps[j] = f2b(W[(k0 + j)*64 + n]);
    const int byte = n*256 + ((k0*2) ^ ((n & 7) << 4));
    *(uint4*)((char*)Wt + byte) = pk;
  }
  __syncthreads();

  const int wv   = tid >> 6;
  const int lane = tid & 63;
  const int g    = lane >> 4;     // k-group (0..3)
  const int c    = lane & 15;     // col/row low index

  // Hoist all 16 B-fragments (whole W) into VGPRs.
  bf16x8 wfrag[4][4];             // [ktile][ntile]
  #pragma unroll
  for (int kt = 0; kt < 4; kt++) {
    #pragma unroll
    for (int nt = 0; nt < 4; nt++) {
      const int n  = nt*16 + c;
      const int kb = (kt*32 + g*8) * 2;
      const int byte = n*256 + (kb ^ ((n & 7) << 4));
      wfrag[kt][nt] = *(bf16x8*)((char*)Wt + byte);
    }
  }
  float a1r[4], a2r[4];
  #pragma unroll
  for (int t = 0; t < 4; t++) { a1r[t] = av[t*16 + c]; a2r[t] = av[64 + t*16 + c]; }

  for (int ch = blockIdx.x*4 + wv; ch < CHUNKS; ch += gridDim.x*4) {
    const int r0 = ch * 16;
    const float* rowp = in + (long)(r0 + c)*128 + g*8;
    float4 ald[8];
    #pragma unroll
    for (int kt = 0; kt < 4; kt++) {
      ald[kt*2]   = *(const float4*)(rowp + kt*32);
      ald[kt*2+1] = *(const float4*)(rowp + kt*32 + 4);
    }
    f32x4 acc[4];
    #pragma unroll
    for (int nt = 0; nt < 4; nt++) acc[nt] = (f32x4){0.f, 0.f, 0.f, 0.f};
    #pragma unroll
    for (int kt = 0; kt < 4; kt++) {
      const float4 u = ald[kt*2], w = ald[kt*2+1];
      bf16x8 af;
      af[0] = (short)f2b(u.x); af[1] = (short)f2b(u.y);
      af[2] = (short)f2b(u.z); af[3] = (short)f2b(u.w);
      af[4] = (short)f2b(w.x); af[5] = (short)f2b(w.y);
      af[6] = (short)f2b(w.z); af[7] = (short)f2b(w.w);
      #pragma unroll
      for (int nt = 0; nt < 4; nt++)
        acc[nt] = __builtin_amdgcn_mfma_f32_16x16x32_bf16(af, wfrag[kt][nt], acc[nt], 0, 0, 0);
    }
    // C/D layout: col = nt*16 + (lane&15), row = g*4 + reg
    // score dots in fp32 (s1 error is common-mode per node -> cancels in softmax)
    float q1v[4], q2v[4];
    #pragma unroll
    for (int v = 0; v < 4; v++) {
      float t1 = 0.f, t2 = 0.f;
      #pragma unroll
      for (int nt = 0; nt < 4; nt++) {
        t1 = fmaf(acc[nt][v], a1r[nt], t1);
        t2 = fmaf(acc[nt][v], a2r[nt], t2);
      }
      #pragma unroll
      for (int off = 1; off < 16; off <<= 1) {
        t1 += __shfl_xor(t1, off);
        t2 += __shfl_xor(t2, off);
      }
      q1v[v] = t1; q2v[v] = t2;
    }
    if (c < 4) {
      const float sv1 = (c==0) ? q1v[0] : (c==1) ? q1v[1] : (c==2) ? q1v[2] : q1v[3];
      const float sv2 = (c==0) ? q2v[0] : (c==1) ? q2v[1] : (c==2) ? q2v[2] : q2v[3];
      const int r = r0 + g*4 + c;
      s1ne[(long)r*2 + pass] = sv1;
      s2ne[(long)r*2 + pass] = sv2;
    }
    #pragma unroll
    for (int nt = 0; nt < 4; nt++) {
      #pragma unroll
      for (int v = 0; v < 4; v++) {
        const float x = acc[nt][v];
        const long r = r0 + g*4 + v;
        outhalf[r*128 + nt*16 + c] = x;       // exact fp32 first half
        tab[r*64 + nt*16 + c]     = f2b(x);   // bf16 gather table
      }
    }
  }
}

// K2: wave-per-node attention + gather-accumulate (second halves only)
__global__ __launch_bounds__(256) void attn_kernel(
    const __hip_bfloat16* __restrict__ hvb, const __hip_bfloat16* __restrict__ evb,
    const float2* __restrict__ s1ne, const float2* __restrict__ s2ne,
    const int* __restrict__ edges,
    float* __restrict__ outp, double* __restrict__ partials)
{
  const int tid  = threadIdx.x;
  const int wv   = tid >> 6;
  const int lane = tid & 63;
  double a_qn = 0.0, a_qe = 0.0;
  float* node_out = outp;
  float* edge_out = outp + (long)NN*128;
  for (int i = blockIdx.x*4 + wv; i < NN; i += gridDim.x*4) {
    const float2 s1v = s1ne[i];
    int dk = 0;
    float attn = 0.f, atte = 0.f;
    if (lane < 16) {
      dk = edges[((long)i*16 + lane)*2 + 1];
      const float2 gsc = s2ne[dk];
      float xn = s1v.x + gsc.x;
      float xe = s1v.y + gsc.y;
      xn = xn > 0.f ? xn : 0.2f*xn;
      xe = xe > 0.f ? xe : 0.2f*xe;
      xn = fminf(fmaxf(xn, -2.f), 2.f);
      xe = fminf(fmaxf(xe, -2.f), 2.f);
      attn = expf(xn);
      atte = expf(xe);
    }
    float sn = attn, se = atte;
    #pragma unroll
    for (int off = 1; off < 16; off <<= 1) {
      sn += __shfl_xor(sn, off);
      se += __shfl_xor(se, off);
    }
    float wn = 0.f, we = 0.f;
    if (lane < 16) { wn = attn / sn; we = atte / se; }
    float rq_n = wn*wn, rq_e = we*we;
    #pragma unroll
    for (int off = 1; off < 16; off <<= 1) {
      rq_n += __shfl_xor(rq_n, off);
      rq_e += __shfl_xor(rq_e, off);
    }
    if (lane == 0) { a_qn += (double)rq_n; a_qe += (double)rq_e; }
    float accn = 0.f, acce = 0.f;
    #pragma unroll
    for (int k = 0; k < 16; k++) {
      const int d     = __shfl(dk, k);
      const float wnk = __shfl(wn, k);
      const float wek = __shfl(we, k);
      accn = fmaf(wnk, __bfloat162float(hvb[(long)d*64 + lane]), accn);
      acce = fmaf(wek, __bfloat162float(evb[(long)d*64 + lane]), acce);
    }
    node_out[(long)i*128 + 64 + lane] = accn;
    edge_out[(long)i*128 + 64 + lane] = acce;
  }
  __shared__ double red[4][2];
  if (lane == 0) { red[wv][0] = a_qn; red[wv][1] = a_qe; }
  __syncthreads();
  if (tid == 0) {
    double t0 = 0, t1 = 0;
    #pragma unroll
    for (int w = 0; w < 4; w++) { t0 += red[w][0]; t1 += red[w][1]; }
    double* p = partials + (long)blockIdx.x*2;
    p[0] = t0; p[1] = t1;
  }
}

// K3: reduce partials -> the two variance scalars (sum of weights is exactly N)
__global__ __launch_bounds__(256) void finalize_kernel(
    const double* __restrict__ partials, int nparts, float* __restrict__ outp)
{
  const int tid = threadIdx.x;
  double l0 = 0, l1 = 0;
  for (int b = tid; b < nparts; b += 256) {
    l0 += partials[b*2+0]; l1 += partials[b*2+1];
  }
  __shared__ double red[256][2];
  red[tid][0] = l0; red[tid][1] = l1;
  __syncthreads();
  for (int s = 128; s > 0; s >>= 1) {
    if (tid < s) {
      red[tid][0] += red[tid+s][0];
      red[tid][1] += red[tid+s][1];
    }
    __syncthreads();
  }
  if (tid == 0) {
    const double E = (double)EE;
    const double S = (double)NN;
    double varn = (red[0][0] - S*S/E) / (E - 1.0);
    double vare = (red[0][1] - S*S/E) / (E - 1.0);
    outp[(long)NN*256 + 0] = (float)varn;
    outp[(long)NN*256 + 1] = (float)vare;
  }
}

extern "C" void kernel_launch(void* const* d_in, const int* in_sizes, int n_in,
                              void* d_out, int out_size, void* d_ws, size_t ws_size,
                              hipStream_t stream)
{
  const float* node_fts = (const float*)d_in[0];
  const float* edge_fts = (const float*)d_in[1];
  const int*   edges    = (const int*)d_in[2];
  const float* W_node   = (const float*)d_in[3];
  const float* W_edge   = (const float*)d_in[4];
  const float* a_node   = (const float*)d_in[5];
  const float* a_edge   = (const float*)d_in[6];

  char* ws = (char*)d_ws;
  unsigned short* hvb = (unsigned short*)(ws);
  unsigned short* evb = (unsigned short*)(ws + 6400000);
  float* s1ne = (float*)(ws + 12800000);
  float* s2ne = (float*)(ws + 13200000);
  double* partials = (double*)(ws + 13600000);
  float* outp = (float*)d_out;

  hipLaunchKernelGGL(gemm_mfma_kernel, dim3(391, 2), dim3(256), 0, stream,
                     node_fts, edge_fts, W_node, W_edge, a_node, a_edge,
                     hvb, evb, s1ne, s2ne, outp);
  const int AB = 2048;
  hipLaunchKernelGGL(attn_kernel, dim3(AB), dim3(256), 0, stream,
                     (const __hip_bfloat16*)hvb, (const __hip_bfloat16*)evb,
                     (const float2*)s1ne, (const float2*)s2ne,
                     edges, outp, partials);
  hipLaunchKernelGGL(finalize_kernel, dim3(1), dim3(256), 0, stream,
                     partials, AB, outp);
}